// Round 1
// 497.360 us; speedup vs baseline: 1.0738x; 1.0738x over previous
//
#include <hip/hip_runtime.h>
#include <stdint.h>

// B=128, N=4096, IN=128, OUT=64
// out[b,n,o] = T * ( LN(x[b,n,:]) @ W_eff + b1[0,n,:] )[o],  W_eff[i,o] = sum_g w1[i,o,g]
// LN refactor with T folded into the weights:
//   Wfrag = bf16(T*gamma*W), GwT[o] = T*sum_i gamma[i]*W[i,o],
//   b1adj[n,o] = T*(b1[n,o] + sum_i beta[i]*W[i,o])
//   out = rs*acc + (-rs*mu)*GwT + b1adj          (2 FMA per element)
// Matvec via mfma_f32_16x16x32_bf16: M=524288 rows, N(out)=64, K=128.

constexpr int   Ndim = 4096;
constexpr int   IN   = 128;
constexpr int   OUT  = 64;
constexpr float EPS  = 1e-5f;

typedef __bf16 bf16x8 __attribute__((ext_vector_type(8)));
typedef unsigned short ushort8 __attribute__((ext_vector_type(8)));
typedef float f32x4 __attribute__((ext_vector_type(4)));
typedef float f32x2 __attribute__((ext_vector_type(2)));
typedef unsigned int u32x4 __attribute__((ext_vector_type(4)));

__device__ __forceinline__ unsigned short f2bf_rne(float f) {
    unsigned int u = __float_as_uint(f);
    u = (u + 0x7FFFu + ((u >> 16) & 1u)) >> 16;   // round-to-nearest-even
    return (unsigned short)u;
}

// HW packed f32->bf16 (RNE), 2 elements per instruction.
__device__ __forceinline__ unsigned int cvt_pk_bf16(float lo, float hi) {
    unsigned int r;
    asm("v_cvt_pk_bf16_f32 %0, %1, %2" : "=v"(r) : "v"(lo), "v"(hi));
    return r;
}

// ---------------- Kernel A: w1 (128,64,4096) -> Weff (128,64) ----------------
// One wave per (i,o) pair; 16 float4 loads/lane in flight; no LDS, no barrier.
__global__ __launch_bounds__(256) void reduce_w_kernel(
    const float* __restrict__ w1, float* __restrict__ Weff)
{
    const int p    = blockIdx.x * 4 + (threadIdx.x >> 6);   // pair in [0, 8192)
    const int lane = threadIdx.x & 63;
    const float4* w4 = (const float4*)(w1 + (long)p * Ndim);

    float s = 0.f;
    #pragma unroll
    for (int j = 0; j < 16; ++j) {
        float4 v = w4[j * 64 + lane];          // coalesced 1KB/wave per load
        s += (v.x + v.y) + (v.z + v.w);
    }
    #pragma unroll
    for (int m = 1; m <= 32; m <<= 1) s += __shfl_xor(s, m);
    if (lane == 0) Weff[p] = s;
}

// ---------------- Kernel C: prep GwT, TBw, Wfrag, b1adj ----------------
// Grid = 64 blocks (1 if !do_adj). Every block redundantly computes Gw/Bw from
// Weff (cheap, L2-hot); block b computes b1adj rows n in [64b, 64b+64);
// block 0 additionally writes GwT, TBw and the T*gamma-scaled bf16 B-fragments.
// Wfrag[kt(4)][nt(4)][lane(64)][j(8)] = bf16( T * gamma[k] * Weff[k][n] )
//   k = kt*32 + (lane>>4)*8 + j, n = nt*16 + (lane&15)   (MFMA B-operand layout)
__global__ __launch_bounds__(256) void prep_kernel(
    const float* __restrict__ Weff,
    const float* __restrict__ gamma,
    const float* __restrict__ beta,
    const float* __restrict__ b1,
    const float* __restrict__ Tp,
    float* __restrict__ GwT, float* __restrict__ TBw,
    unsigned short* __restrict__ Wfrag,
    float* __restrict__ b1adj, int do_adj)
{
    const int tid = threadIdx.x;
    __shared__ float Ws[IN * OUT];
    __shared__ float gs[IN], bs[IN];
    __shared__ float redg[256], redb[256];
    __shared__ float Bws[OUT];
    const float Tv = Tp[0];

    #pragma unroll
    for (int k = 0; k < 32; ++k) Ws[k * 256 + tid] = Weff[k * 256 + tid];
    if (tid < IN) { gs[tid] = gamma[tid]; bs[tid] = beta[tid]; }
    __syncthreads();

    // 256-thread parallel column sums: o = tid&63, 4 groups of 32 i's each.
    {
        const int o = tid & 63, grp = tid >> 6;
        float gw = 0.f, bw = 0.f;
        #pragma unroll
        for (int ii = 0; ii < 32; ++ii) {
            int i = grp * 32 + ii;
            float w = Ws[i * OUT + o];
            gw = fmaf(gs[i], w, gw);
            bw = fmaf(bs[i], w, bw);
        }
        redg[tid] = gw; redb[tid] = bw;
    }
    __syncthreads();
    if (tid < OUT) {
        float bwf = redb[tid] + redb[64 + tid] + redb[128 + tid] + redb[192 + tid];
        Bws[tid] = bwf;
        if (blockIdx.x == 0) {
            float gwf = redg[tid] + redg[64 + tid] + redg[128 + tid] + redg[192 + tid];
            GwT[tid] = Tv * gwf;
            TBw[tid] = Tv * bwf;
        }
    }
    __syncthreads();

    // b1adj slice: 64 rows x 64 cols = 4096 floats, 16 per thread, f32x4.
    if (do_adj) {
        const float* src = b1 + (long)blockIdx.x * 64 * OUT;
        float*       dst = b1adj + (long)blockIdx.x * 64 * OUT;
        #pragma unroll
        for (int v = 0; v < 4; ++v) {
            int e = tid * 16 + v * 4;
            f32x4 t = *(const f32x4*)(src + e);
            #pragma unroll
            for (int j = 0; j < 4; ++j)
                t[j] = Tv * (t[j] + Bws[(e + j) & 63]);
            *(f32x4*)(dst + e) = t;
        }
    }

    if (blockIdx.x != 0) return;

    #pragma unroll
    for (int t = 0; t < 32; ++t) {
        int e    = t * 256 + tid;          // [0, 8192)
        int j    = e & 7;
        int lane = (e >> 3) & 63;
        int pr   = e >> 9;                 // kt*4 + nt
        int kt   = pr >> 2, nt = pr & 3;
        int k    = kt * 32 + ((lane >> 4) << 3) + j;
        int n    = nt * 16 + (lane & 15);
        Wfrag[e] = f2bf_rne(Tv * gs[k] * Ws[k * OUT + n]);
    }
}

// ---------------- Kernel B: fused LN + MFMA matvec + bias + T ----------------
// 4 waves/block; each wave does 4 chunks of 16 rows. Per chunk:
//   A-frag: lane holds x[row0+(lane&15)][ (lane>>4)*8 + kt*32 .. +8 ]  (fp32->bf16)
//   stats:  lane's 32 x-values union over lanes {L,L^16,L^32,L^48} = full row
//   C-tile: col = lane&15 (-> o = nt*16+col), row = (lane>>4)*4 + reg
constexpr int ROWS_PER_BLOCK = 256;   // grid = 524288/256 = 2048

template<bool ADJ>
__global__ __launch_bounds__(256, 3) void fused_mfma_kernel(
    const float* __restrict__ x,
    const unsigned short* __restrict__ Wfrag,
    const float* __restrict__ GwT,
    const float* __restrict__ TBw,
    const float* __restrict__ b1a,   // ADJ ? T*(b1+Bw) : raw b1
    const float* __restrict__ Tp,
    float* __restrict__ out)
{
    const int tid  = threadIdx.x;
    const int wave = tid >> 6;
    const int lane = tid & 63;
    const int q    = lane >> 4;     // quad index
    const int mloc = lane & 15;     // row (A) / col (C) within 16-tile

    // --- B fragments: 16 coalesced dwordx4 loads, held for whole kernel ---
    bf16x8 bfr[4][4];
    const ushort8* wf8 = (const ushort8*)Wfrag;
    #pragma unroll
    for (int kt = 0; kt < 4; ++kt)
        #pragma unroll
        for (int nt = 0; nt < 4; ++nt) {
            ushort8 u = wf8[(kt * 4 + nt) * 64 + lane];
            bfr[kt][nt] = __builtin_bit_cast(bf16x8, u);
        }

    float GwTl[4], TBwl[4];
    #pragma unroll
    for (int nt = 0; nt < 4; ++nt) {
        GwTl[nt] = GwT[nt * 16 + mloc];
        TBwl[nt] = ADJ ? 0.f : TBw[nt * 16 + mloc];
    }
    const float Tv = ADJ ? 1.f : Tp[0];

    const long wave_row0 = (long)blockIdx.x * ROWS_PER_BLOCK + wave * 64;

    #pragma unroll
    for (int c = 0; c < 4; ++c) {
        const long row0 = wave_row0 + c * 16;

        // ---- Load 16 rows directly in A-fragment order ----
        const float* xr = x + (row0 + mloc) * IN + q * 8;
        f32x4 xv[8];
        #pragma unroll
        for (int kt = 0; kt < 4; ++kt) {
            xv[2 * kt]     = *(const f32x4*)(xr + kt * 32);
            xv[2 * kt + 1] = *(const f32x4*)(xr + kt * 32 + 4);
        }

        // ---- LN stats, packed f32x2 (v_pk_add_f32 / v_pk_fma_f32) ----
        f32x2 sp = {0.f, 0.f}, qp = {0.f, 0.f};
        #pragma unroll
        for (int v = 0; v < 8; ++v) {
            f32x2 a = __builtin_shufflevector(xv[v], xv[v], 0, 1);
            f32x2 b = __builtin_shufflevector(xv[v], xv[v], 2, 3);
            sp += a;          sp += b;
            qp  = a * a + qp; qp  = b * b + qp;
        }
        float s  = sp[0] + sp[1];
        float s2 = qp[0] + qp[1];
        s  += __shfl_xor(s, 16);  s  += __shfl_xor(s, 32);
        s2 += __shfl_xor(s2, 16); s2 += __shfl_xor(s2, 32);
        float mu  = s * (1.f / IN);
        float var = fmaf(-mu, mu, s2 * (1.f / IN));
        float rs  = rsqrtf(var + EPS);
        float nb  = -rs * mu;          // broadcast -rs*mu instead of mu

        // ---- Convert to bf16 A-fragments via HW v_cvt_pk_bf16_f32 ----
        bf16x8 af[4];
        #pragma unroll
        for (int kt = 0; kt < 4; ++kt) {
            u32x4 w;
            w[0] = cvt_pk_bf16(xv[2 * kt][0],     xv[2 * kt][1]);
            w[1] = cvt_pk_bf16(xv[2 * kt][2],     xv[2 * kt][3]);
            w[2] = cvt_pk_bf16(xv[2 * kt + 1][0], xv[2 * kt + 1][1]);
            w[3] = cvt_pk_bf16(xv[2 * kt + 1][2], xv[2 * kt + 1][3]);
            af[kt] = __builtin_bit_cast(bf16x8, w);
        }

        // ---- MFMA: 16 per chunk ----
        f32x4 acc[4] = {{0.f,0.f,0.f,0.f},{0.f,0.f,0.f,0.f},
                        {0.f,0.f,0.f,0.f},{0.f,0.f,0.f,0.f}};
        #pragma unroll
        for (int kt = 0; kt < 4; ++kt)
            #pragma unroll
            for (int nt = 0; nt < 4; ++nt)
                acc[nt] = __builtin_amdgcn_mfma_f32_16x16x32_bf16(
                              af[kt], bfr[kt][nt], acc[nt], 0, 0, 0);

        // ---- Epilogue: 2 FMA per element ----
        #pragma unroll
        for (int r = 0; r < 4; ++r) {
            int   rloc = q * 4 + r;
            float rsr  = __shfl(rs, rloc);
            float nbr  = __shfl(nb, rloc);
            long  row  = row0 + rloc;
            int   n    = (int)(row & (Ndim - 1));
            const float* brow = b1a + (long)n * OUT;
            #pragma unroll
            for (int nt = 0; nt < 4; ++nt) {
                int   o    = nt * 16 + mloc;
                float base = ADJ ? brow[o] : fmaf(Tv, brow[o], TBwl[nt]);
                float val  = fmaf(rsr, acc[nt][r], fmaf(nbr, GwTl[nt], base));
                out[row * OUT + o] = val;
            }
        }
    }
}

extern "C" void kernel_launch(void* const* d_in, const int* in_sizes, int n_in,
                              void* d_out, int out_size, void* d_ws, size_t ws_size,
                              hipStream_t stream)
{
    const float* x     = (const float*)d_in[0];
    const float* gamma = (const float*)d_in[1];
    const float* beta  = (const float*)d_in[2];
    const float* w1    = (const float*)d_in[3];
    const float* b1    = (const float*)d_in[4];
    const float* T     = (const float*)d_in[5];
    float*       out   = (float*)d_out;

    float*          ws    = (float*)d_ws;
    float*          Weff  = ws;                          // 8192 f
    float*          GwT   = ws + 8192;                   // 64 f
    float*          TBw   = ws + 8256;                   // 64 f
    unsigned short* Wfrag = (unsigned short*)(ws + 8320);// 8192 u16 (4096 f)
    float*          b1adj = ws + 12416;                  // 262144 f (1 MB)

    const size_t NEED = (size_t)(12416 + 262144) * sizeof(float);
    const bool   adj  = ws_size >= NEED;

    // A: w1 (128,64,4096) -> Weff (128,64).  8192 pairs / 4 waves = 2048 blocks.
    reduce_w_kernel<<<2048, 256, 0, stream>>>(w1, Weff);

    // C: GwT/TBw + T*gamma-scaled bf16 W fragments + b1adj (parallel, 64 blocks).
    prep_kernel<<<adj ? 64 : 1, 256, 0, stream>>>(
        Weff, gamma, beta, b1, T, GwT, TBw, Wfrag, b1adj, adj ? 1 : 0);

    // B: fused LN + MFMA matvec + bias + temperature.
    const long rows = 128L * 4096L;
    if (adj)
        fused_mfma_kernel<true ><<<rows / ROWS_PER_BLOCK, 256, 0, stream>>>(
            x, Wfrag, GwT, TBw, b1adj, T, out);
    else
        fused_mfma_kernel<false><<<rows / ROWS_PER_BLOCK, 256, 0, stream>>>(
            x, Wfrag, GwT, TBw, b1, T, out);
}